// Round 9
// baseline (222.633 us; speedup 1.0000x reference)
//
#include <hip/hip_runtime.h>
#include <cstdint>

// CTC loss, tf.nn.ctc_loss semantics (blank_index=0), B=1024 T=256 C=128 L=32.
// One block (512 thr = 8 waves) per batch element.
//
// Round-9: R8 post-mortem — per-chunk __syncthreads (+ compiler's
// conservative vmcnt(0) before ds_read after a global_load_lds issue) made
// the "async" pipeline fully synchronous: ~1 KB in flight per block =
// 1.7 TB/s effective. Fix: NO barriers in phase 1. Each wave consumes
// exactly the bytes it loads (wave w owns rows 2w,2w+1 of each 16-row
// chunk), so per-wave vmcnt ordering suffices. 32 independent self-paced
// wave pipelines/CU demand ~70 GB/s/CU >> 24.6 fair share -> HBM-bound
// even under worst-case per-wave serialization. One barrier total, then
// wave 0 runs the 256-step DP.

#define CTC_BLANK 0
#define CTC_PAD   127
#define NEG       (-1e30f)
#define LOG2E     1.44269504088896340736f
#define LN2       0.69314718055994530942f

constexpr int Bn = 1024, Tn = 256, Cn = 128, Ln = 32;
constexpr int NSLOT = Ln + 1;     // 33: blank + up to 32 distinct labels
constexpr int CR  = 16;           // rows per chunk (2 per wave)
constexpr int NCH = Tn / CR;      // 16 chunks

__device__ __forceinline__ float fexp2(float x) { return __builtin_amdgcn_exp2f(x); }
__device__ __forceinline__ float flog2(float x) { return __builtin_amdgcn_logf(x); }

// s += dpp_shift(s); invalid source lanes contribute 0 (bound_ctrl:0).
template <int CTRL>
__device__ __forceinline__ float dpp_add(float s) {
    int v = __builtin_amdgcn_update_dpp(0, __float_as_int(s), CTRL, 0xF, 0xF, true);
    return s + __int_as_float(v);
}
// lane i <- src[lane i-1]; lane 0 <- old.  (wave_shr:1, VALU pipe)
__device__ __forceinline__ float dpp_wave_shr1(float src, float old) {
    return __int_as_float(__builtin_amdgcn_update_dpp(
        __float_as_int(old), __float_as_int(src), 0x138, 0xF, 0xF, false));
}
// async global->LDS, 16 B/lane; lds base must be wave-uniform (lane i lands
// at base + i*16).
__device__ __forceinline__ void gl_lds16(const float* g, float* l) {
    __builtin_amdgcn_global_load_lds(
        (const __attribute__((address_space(1))) uint32_t*)g,
        (__attribute__((address_space(3))) uint32_t*)l, 16, 0, 0);
}

__global__ __launch_bounds__(512, 8) void ctc_fused_kernel(
        const int*   __restrict__ y_true,   // [B, L]
        const float* __restrict__ y_pred,   // [B, T, C]
        float*       __restrict__ out)      // [B]
{
    __shared__ __align__(16) float raw[8][2][CR / 8 * Cn];  // per-wave 2x1KB
    __shared__ _Float16 Gc[Tn * NSLOT];                     // 16.9 KB, log2
    __shared__ int   labels[Ln];
    __shared__ __align__(16) int cmap[Cn];
    __shared__ int   used[Cn];
    __shared__ int   wcnt[8];
    __shared__ float partS[16];

    const int b    = blockIdx.x;
    const int tid  = threadIdx.x;
    const int lane = tid & 63;
    const int wave = tid >> 6;

    const float* gbase = y_pred + (size_t)b * Tn * Cn;

    // wave w stages its rows {c*16+2w, c*16+2w+1} of chunk c: 1 KB contiguous,
    // one global_load_lds per wave per chunk, per-lane global addr + uniform
    // LDS base (lane lands at base + lane*16).
    auto stage = [&](int c, int buf) {
        const float* g = gbase + (size_t)(c * CR + 2 * wave) * Cn + lane * 4;
        gl_lds16(g, &raw[wave][buf][0]);
    };

    stage(0, 0);   // chunk-0 latency hides behind the cmap build

    // ---- class->slot map ----
    if (tid < Ln) labels[tid] = y_true[b * Ln + tid];
    if (tid < Cn) used[tid] = 0;
    __syncthreads();
    if (tid == 0) used[CTC_BLANK] = 1;
    if (tid < Ln) used[labels[tid]] = 1;   // racy same-value writes: fine
    __syncthreads();
    {
        bool f = (tid < Cn) && (used[tid] != 0);
        unsigned long long m = __ballot(f);
        if (lane == 0) wcnt[wave] = __popcll(m);
        __syncthreads();
        int base = 0;
        for (int w = 0; w < wave; ++w) base += wcnt[w];
        if (tid < Cn)
            cmap[tid] = f ? (base + __popcll(m & ((1ull << lane) - 1ull))) : -1;
        __syncthreads();
    }

    // ---- phase 1: barrier-free per-wave pipelines ----
    // lanes 0-31: row 2w (floats 0..127); lanes 32-63: row 2w+1.
    const int half = lane >> 5;
    const int l32  = lane & 31;
    const int4 cm  = ((const int4*)cmap)[l32];
    float acc = 0.f;

    for (int c = 0; c < NCH; ++c) {
        // read own segment (loaded one iteration ago) ...
        const float4 x = ((const float4*)&raw[wave][c & 1][0])[lane];
        // ... then immediately refill the other buffer
        if (c + 1 < NCH) stage(c + 1, (c + 1) & 1);

        const int r = c * CR + 2 * wave + half;
        if (cm.x >= 0) Gc[r * NSLOT + cm.x] = (_Float16)(x.x * LOG2E);
        if (cm.y >= 0) Gc[r * NSLOT + cm.y] = (_Float16)(x.y * LOG2E);
        if (cm.z >= 0) Gc[r * NSLOT + cm.z] = (_Float16)(x.z * LOG2E);
        if (cm.w >= 0) Gc[r * NSLOT + cm.w] = (_Float16)(x.w * LOG2E);
        float s = __expf(x.x) + __expf(x.y) + __expf(x.z) + __expf(x.w);
        s = dpp_add<0x111>(s);   // row_shr:1
        s = dpp_add<0x112>(s);   // row_shr:2
        s = dpp_add<0x114>(s);   // row_shr:4
        s = dpp_add<0x118>(s);   // row_shr:8
        s = dpp_add<0x142>(s);   // row_bcast:15 (combine 16-lane rows)
        acc += __logf(s);        // valid on lanes 31 / 63
    }
    if (l32 == 31) partS[wave * 2 + half] = acc;
    __syncthreads();   // the ONLY post-setup barrier: publishes Gc + partS

    // ---- phase 2: alpha DP on wave 0 (log2 domain), PF=2 rolling ----
    if (wave == 0) {
        const int  i      = lane;                 // lane i: states 2i, 2i+1
        const bool validO = (i < Ln);
        const bool validE = (i <= Ln);
        const int  myLab   = validO ? labels[i] : -1;
        const int  prevLab = (i >= 1 && i < Ln) ? labels[i - 1] : -1;
        const int  slotO   = validO ? cmap[myLab] : 0;
        const bool skipO   = (i >= 1 && i < Ln) &&
                             (myLab != CTC_BLANK) && (myLab != prevLab);
        const int  len = __popcll(__ballot(validO && (myLab != CTC_PAD)));

        float aE = (i == 0) ? (float)Gc[0]     : NEG;
        float aO = (i == 0) ? (float)Gc[slotO] : NEG;

        float pB[2], pO[2];
        pB[0] = (float)Gc[NSLOT];     pO[0] = (float)Gc[NSLOT + slotO];
        pB[1] = (float)Gc[2 * NSLOT]; pO[1] = (float)Gc[2 * NSLOT + slotO];
        int k = 0;
        #pragma unroll 2
        for (int t = 1; t < Tn; ++t) {
            const float lpB = pB[k], lpO = pO[k];
            const int tp = (t + 2 < Tn) ? t + 2 : Tn - 1;
            pB[k] = (float)Gc[tp * NSLOT];
            pO[k] = (float)Gc[tp * NSLOT + slotO];
            k ^= 1;

            const float aOup = dpp_wave_shr1(aO, NEG);   // alpha[2i-1]
            const float m  = fmaxf(aE, aOup);
            const float e1 = fexp2(aE - m);
            const float e2 = fexp2(aOup - m);
            const float sE = e1 + e2;
            const float nE = lpB + m + flog2(sE);                // s = 2i
            const float m3 = fmaxf(aO, m);
            const float nO = lpO + m3 +                          // s = 2i+1
                flog2(fexp2(aO - m3) + (skipO ? sE : e1) * fexp2(m - m3));
            aE = validE ? nE : NEG;
            aO = validO ? nO : NEG;
        }

        const float v1 = __shfl(aE, len, 64);       // alpha[2*len]
        const float v2 = __shfl(aO, len - 1, 64);   // alpha[2*len-1]
        if (i == 0) {
            float S = 0.f;
            #pragma unroll
            for (int j = 0; j < 16; ++j) S += partS[j];
            const float mm = fmaxf(v1, v2);
            const float L2 = mm + flog2(fexp2(v1 - mm) + fexp2(v2 - mm));
            out[b] = S - LN2 * L2;   // S: natural-log lse sum; L2: log2 domain
        }
    }
}

extern "C" void kernel_launch(void* const* d_in, const int* in_sizes, int n_in,
                              void* d_out, int out_size, void* d_ws, size_t ws_size,
                              hipStream_t stream) {
    const int*   y_true = (const int*)d_in[0];
    const float* y_pred = (const float*)d_in[1];
    float*       out    = (float*)d_out;
    ctc_fused_kernel<<<Bn, 512, 0, stream>>>(y_true, y_pred, out);
}

// Round 10
// 219.887 us; speedup vs baseline: 1.0125x; 1.0125x over previous
//
#include <hip/hip_runtime.h>
#include <cstdint>

// CTC loss, tf.nn.ctc_loss semantics (blank_index=0), B=1024 T=256 C=128 L=32.
//
// Round-10: R6-R9 (four different phase-1 structures) all land at 74-85us ->
// phase 1 is NOT the bottleneck. Occupancy-weighted attribution puts the
// wave-0 alpha-DP tail at ~46-55us, running at only 4 waves/CU in every
// fused design. Fix: split kernels so each phase gets its own occupancy.
//  - ctc_stage: grid (2,1024) x 256thr, 32 waves/CU, gathers logits into a
//    fp16 log2-domain ws [B,T,33] (17.3 MB, L3-resident) via LDS tile +
//    coalesced uint4 dump; per-chunk natural-log lse partials to sws.
//  - ctc_dp: 1024 blocks x 64 thr, 16.9 KB LDS -> 8 blocks/CU; >=2x DP
//    concurrency vs all previous rounds; DP latency chain spread over 1024
//    concurrent waves.

#define CTC_BLANK 0
#define CTC_PAD   127
#define NEG       (-1e30f)
#define LOG2E     1.44269504088896340736f
#define LN2       0.69314718055994530942f

constexpr int Bn = 1024, Tn = 256, Cn = 128, Ln = 32;
constexpr int NSLOT = Ln + 1;     // 33: blank + up to 32 distinct labels
constexpr size_t GC_HALFS  = (size_t)Tn * NSLOT;             // 8448 per b
constexpr size_t WS_GC_B   = (size_t)Bn * GC_HALFS * 2;      // 17,301,504 B
constexpr size_t WS_S_B    = (size_t)Bn * 16 * 4;            // 65,536 B
constexpr size_t WS_NEEDED = WS_GC_B + WS_S_B;

__device__ __forceinline__ float fexp2(float x) { return __builtin_amdgcn_exp2f(x); }
__device__ __forceinline__ float flog2(float x) { return __builtin_amdgcn_logf(x); }

// s += dpp_shift(s); invalid source lanes contribute 0 (bound_ctrl:0).
template <int CTRL>
__device__ __forceinline__ float dpp_add(float s) {
    int v = __builtin_amdgcn_update_dpp(0, __float_as_int(s), CTRL, 0xF, 0xF, true);
    return s + __int_as_float(v);
}
// lane i <- src[lane i-1]; lane 0 <- old.  (wave_shr:1, VALU pipe)
__device__ __forceinline__ float dpp_wave_shr1(float src, float old) {
    return __int_as_float(__builtin_amdgcn_update_dpp(
        __float_as_int(old), __float_as_int(src), 0x138, 0xF, 0xF, false));
}

// ---------------------------------------------------------------------------
// Kernel A: gather + lse partials.  grid (2, Bn), block 256 (4 waves).
// Block (h,b) covers rows [h*128, h*128+128) of batch b.
// ---------------------------------------------------------------------------
__global__ __launch_bounds__(256) void ctc_stage_kernel(
        const int*   __restrict__ y_true,   // [B, L]
        const float* __restrict__ y_pred,   // [B, T, C]
        _Float16*    __restrict__ gws,      // [B, T, 33] log2-domain fp16
        float*       __restrict__ sws)      // [B, 16] natural-log lse partials
{
    __shared__ _Float16 Gt[128 * NSLOT];   // 8448 B gathered tile
    __shared__ int labels[Ln];
    __shared__ __align__(16) int cmap[Cn];
    __shared__ int used[Cn];
    __shared__ int wcnt[4];

    const int h    = blockIdx.x;
    const int b    = blockIdx.y;
    const int tid  = threadIdx.x;
    const int lane = tid & 63;
    const int wave = tid >> 6;

    // ---- class->slot map ----
    if (tid < Ln) labels[tid] = y_true[b * Ln + tid];
    if (tid < Cn) used[tid] = 0;
    __syncthreads();
    if (tid == 0) used[CTC_BLANK] = 1;
    if (tid < Ln) used[labels[tid]] = 1;   // racy same-value writes: fine
    __syncthreads();
    {
        bool f = (tid < Cn) && (used[tid] != 0);
        unsigned long long m = __ballot(f);
        if (lane == 0) wcnt[wave] = __popcll(m);
        __syncthreads();
        int base = 0;
        for (int w = 0; w < wave; ++w) base += wcnt[w];
        if (tid < Cn)
            cmap[tid] = f ? (base + __popcll(m & ((1ull << lane) - 1ull))) : -1;
        __syncthreads();
    }

    // ---- gather 32 rows per wave (16 pairs), double-buffered groups of 4 ----
    // lanes 0-31: row 2p (float4 = 4 classes each), lanes 32-63: row 2p+1.
    const float* rowbase = y_pred + ((size_t)b * Tn + h * 128) * Cn;
    const int half = lane >> 5;
    const int l32  = lane & 31;
    const int4 cm  = ((const int4*)cmap)[l32];
    float acc = 0.f;

    float4 v[2][4];
    #pragma unroll
    for (int j = 0; j < 4; ++j) {
        const int rl = 2 * (wave * 16 + j) + half;
        v[0][j] = ((const float4*)(rowbase + rl * Cn))[l32];
    }
    for (int g = 0; g < 4; ++g) {
        if (g < 3) {
            #pragma unroll
            for (int j = 0; j < 4; ++j) {
                const int rl = 2 * (wave * 16 + (g + 1) * 4 + j) + half;
                v[(g + 1) & 1][j] = ((const float4*)(rowbase + rl * Cn))[l32];
            }
        }
        #pragma unroll
        for (int j = 0; j < 4; ++j) {
            const float4 x = v[g & 1][j];
            const int rl = 2 * (wave * 16 + g * 4 + j) + half;
            if (cm.x >= 0) Gt[rl * NSLOT + cm.x] = (_Float16)(x.x * LOG2E);
            if (cm.y >= 0) Gt[rl * NSLOT + cm.y] = (_Float16)(x.y * LOG2E);
            if (cm.z >= 0) Gt[rl * NSLOT + cm.z] = (_Float16)(x.z * LOG2E);
            if (cm.w >= 0) Gt[rl * NSLOT + cm.w] = (_Float16)(x.w * LOG2E);
            float s = __expf(x.x) + __expf(x.y) + __expf(x.z) + __expf(x.w);
            s = dpp_add<0x111>(s);   // row_shr:1
            s = dpp_add<0x112>(s);   // row_shr:2
            s = dpp_add<0x114>(s);   // row_shr:4
            s = dpp_add<0x118>(s);   // row_shr:8
            s = dpp_add<0x142>(s);   // row_bcast:15
            acc += __logf(s);        // valid on lanes 31 / 63
        }
    }
    if (l32 == 31) sws[b * 16 + h * 8 + wave * 2 + half] = acc;
    __syncthreads();

    // ---- coalesced dump: 8448 B = 528 uint4 ----
    {
        uint4*       dst = (uint4*)(gws + ((size_t)b * Tn + h * 128) * NSLOT);
        const uint4* src = (const uint4*)Gt;
        dst[tid]       = src[tid];
        dst[256 + tid] = src[256 + tid];
        if (tid < 16) dst[512 + tid] = src[512 + tid];
    }
}

// ---------------------------------------------------------------------------
// Kernel B: alpha DP.  grid Bn, block 64 (one wave). 16.9 KB LDS -> up to
// 8 blocks/CU; >=1024 concurrent DP waves chip-wide.
// ---------------------------------------------------------------------------
__global__ __launch_bounds__(64) void ctc_dp_kernel(
        const int*      __restrict__ y_true,
        const _Float16* __restrict__ gws,
        const float*    __restrict__ sws,
        float*          __restrict__ out)
{
    __shared__ __align__(16) _Float16 Gc[GC_HALFS];   // 16896 B
    __shared__ int labels[Ln];
    __shared__ int used[Cn];
    __shared__ int cmap[Cn];

    const int b    = blockIdx.x;
    const int lane = threadIdx.x;

    // ---- stage Gc slice: 1056 uint4, coalesced ----
    {
        const uint4* src = (const uint4*)(gws + (size_t)b * GC_HALFS);
        uint4*       dst = (uint4*)Gc;
        #pragma unroll
        for (int k = 0; k < 17; ++k) {
            const int idx = k * 64 + lane;
            if (idx < 1056) dst[idx] = src[idx];
        }
    }

    // ---- rebuild class->slot map (single wave, 2 classes/lane) ----
    if (lane < Ln) labels[lane] = y_true[b * Ln + lane];
    used[lane] = 0; used[64 + lane] = 0;
    __syncthreads();
    if (lane == 0) used[CTC_BLANK] = 1;
    if (lane < Ln) used[labels[lane]] = 1;
    __syncthreads();
    {
        const unsigned long long below = (1ull << lane) - 1ull;
        const unsigned long long m0 = __ballot(used[lane] != 0);
        const unsigned long long m1 = __ballot(used[64 + lane] != 0);
        cmap[lane]      = used[lane]      ? (int)__popcll(m0 & below) : -1;
        cmap[64 + lane] = used[64 + lane] ? (int)(__popcll(m0) +
                                                  __popcll(m1 & below)) : -1;
    }
    __syncthreads();

    // ---- DP: lane i holds states 2i (blank) and 2i+1 (label i) ----
    const int  i      = lane;
    const bool validO = (i < Ln);
    const bool validE = (i <= Ln);
    const int  myLab   = validO ? labels[i] : -1;
    const int  prevLab = (i >= 1 && i < Ln) ? labels[i - 1] : -1;
    const int  slotO   = validO ? cmap[myLab] : 0;
    const bool skipO   = (i >= 1 && i < Ln) &&
                         (myLab != CTC_BLANK) && (myLab != prevLab);
    const int  len = __popcll(__ballot(validO && (myLab != CTC_PAD)));

    float aE = (i == 0) ? (float)Gc[0]     : NEG;
    float aO = (i == 0) ? (float)Gc[slotO] : NEG;

    float pB[2], pO[2];
    pB[0] = (float)Gc[NSLOT];     pO[0] = (float)Gc[NSLOT + slotO];
    pB[1] = (float)Gc[2 * NSLOT]; pO[1] = (float)Gc[2 * NSLOT + slotO];
    int k = 0;
    #pragma unroll 2
    for (int t = 1; t < Tn; ++t) {
        const float lpB = pB[k], lpO = pO[k];
        const int tp = (t + 2 < Tn) ? t + 2 : Tn - 1;
        pB[k] = (float)Gc[tp * NSLOT];
        pO[k] = (float)Gc[tp * NSLOT + slotO];
        k ^= 1;

        const float aOup = dpp_wave_shr1(aO, NEG);   // alpha[2i-1]
        const float m  = fmaxf(aE, aOup);
        const float e1 = fexp2(aE - m);
        const float e2 = fexp2(aOup - m);
        const float sE = e1 + e2;
        const float nE = lpB + m + flog2(sE);                // s = 2i
        const float m3 = fmaxf(aO, m);
        const float nO = lpO + m3 +                          // s = 2i+1
            flog2(fexp2(aO - m3) + (skipO ? sE : e1) * fexp2(m - m3));
        aE = validE ? nE : NEG;
        aO = validO ? nO : NEG;
    }

    const float v1 = __shfl(aE, len, 64);       // alpha[2*len]
    const float v2 = __shfl(aO, len - 1, 64);   // alpha[2*len-1]
    if (i == 0) {
        float S = 0.f;
        #pragma unroll
        for (int j = 0; j < 16; ++j) S += sws[b * 16 + j];
        const float mm = fmaxf(v1, v2);
        const float L2 = mm + flog2(fexp2(v1 - mm) + fexp2(v2 - mm));
        out[b] = S - LN2 * L2;   // S: natural-log lse sum; L2: log2 domain
    }
}

// ---------------------------------------------------------------------------
// Fallback (ws too small): round-9 fused kernel (passed, 84us).
// ---------------------------------------------------------------------------
__global__ __launch_bounds__(512, 8) void ctc_fused_kernel(
        const int*   __restrict__ y_true,
        const float* __restrict__ y_pred,
        float*       __restrict__ out)
{
    __shared__ _Float16 Gc[Tn * NSLOT];
    __shared__ int   labels[Ln];
    __shared__ __align__(16) int cmap[Cn];
    __shared__ int   used[Cn];
    __shared__ int   wcnt[8];
    __shared__ float partS[16];

    const int b    = blockIdx.x;
    const int tid  = threadIdx.x;
    const int lane = tid & 63;
    const int wave = tid >> 6;

    if (tid < Ln) labels[tid] = y_true[b * Ln + tid];
    if (tid < Cn) used[tid] = 0;
    __syncthreads();
    if (tid == 0) used[CTC_BLANK] = 1;
    if (tid < Ln) used[labels[tid]] = 1;
    __syncthreads();
    {
        bool f = (tid < Cn) && (used[tid] != 0);
        unsigned long long m = __ballot(f);
        if (lane == 0) wcnt[wave] = __popcll(m);
        __syncthreads();
        int base = 0;
        for (int w = 0; w < wave; ++w) base += wcnt[w];
        if (tid < Cn)
            cmap[tid] = f ? (base + __popcll(m & ((1ull << lane) - 1ull))) : -1;
        __syncthreads();
    }

    const float* rowbase = y_pred + (size_t)b * Tn * Cn;
    const int half = lane >> 5;
    const int l32  = lane & 31;
    const int4 cm  = ((const int4*)cmap)[l32];
    float acc = 0.f;
    for (int c = 0; c < 16; ++c) {
        const int r = c * 16 + 2 * wave + half;
        const float4 x = ((const float4*)(rowbase + r * Cn))[l32];
        if (cm.x >= 0) Gc[r * NSLOT + cm.x] = (_Float16)(x.x * LOG2E);
        if (cm.y >= 0) Gc[r * NSLOT + cm.y] = (_Float16)(x.y * LOG2E);
        if (cm.z >= 0) Gc[r * NSLOT + cm.z] = (_Float16)(x.z * LOG2E);
        if (cm.w >= 0) Gc[r * NSLOT + cm.w] = (_Float16)(x.w * LOG2E);
        float s = __expf(x.x) + __expf(x.y) + __expf(x.z) + __expf(x.w);
        s = dpp_add<0x111>(s);
        s = dpp_add<0x112>(s);
        s = dpp_add<0x114>(s);
        s = dpp_add<0x118>(s);
        s = dpp_add<0x142>(s);
        acc += __logf(s);
    }
    if (l32 == 31) partS[wave * 2 + half] = acc;
    __syncthreads();

    if (wave == 0) {
        const int  i      = lane;
        const bool validO = (i < Ln);
        const bool validE = (i <= Ln);
        const int  myLab   = validO ? labels[i] : -1;
        const int  prevLab = (i >= 1 && i < Ln) ? labels[i - 1] : -1;
        const int  slotO   = validO ? cmap[myLab] : 0;
        const bool skipO   = (i >= 1 && i < Ln) &&
                             (myLab != CTC_BLANK) && (myLab != prevLab);
        const int  len = __popcll(__ballot(validO && (myLab != CTC_PAD)));

        float aE = (i == 0) ? (float)Gc[0]     : NEG;
        float aO = (i == 0) ? (float)Gc[slotO] : NEG;
        float pB[2], pO[2];
        pB[0] = (float)Gc[NSLOT];     pO[0] = (float)Gc[NSLOT + slotO];
        pB[1] = (float)Gc[2 * NSLOT]; pO[1] = (float)Gc[2 * NSLOT + slotO];
        int k = 0;
        #pragma unroll 2
        for (int t = 1; t < Tn; ++t) {
            const float lpB = pB[k], lpO = pO[k];
            const int tp = (t + 2 < Tn) ? t + 2 : Tn - 1;
            pB[k] = (float)Gc[tp * NSLOT];
            pO[k] = (float)Gc[tp * NSLOT + slotO];
            k ^= 1;
            const float aOup = dpp_wave_shr1(aO, NEG);
            const float m  = fmaxf(aE, aOup);
            const float e1 = fexp2(aE - m);
            const float e2 = fexp2(aOup - m);
            const float sE = e1 + e2;
            const float nE = lpB + m + flog2(sE);
            const float m3 = fmaxf(aO, m);
            const float nO = lpO + m3 +
                flog2(fexp2(aO - m3) + (skipO ? sE : e1) * fexp2(m - m3));
            aE = validE ? nE : NEG;
            aO = validO ? nO : NEG;
        }
        const float v1 = __shfl(aE, len, 64);
        const float v2 = __shfl(aO, len - 1, 64);
        if (i == 0) {
            float S = 0.f;
            #pragma unroll
            for (int j = 0; j < 16; ++j) S += partS[j];
            const float mm = fmaxf(v1, v2);
            const float L2 = mm + flog2(fexp2(v1 - mm) + fexp2(v2 - mm));
            out[b] = S - LN2 * L2;
        }
    }
}

extern "C" void kernel_launch(void* const* d_in, const int* in_sizes, int n_in,
                              void* d_out, int out_size, void* d_ws, size_t ws_size,
                              hipStream_t stream) {
    const int*   y_true = (const int*)d_in[0];
    const float* y_pred = (const float*)d_in[1];
    float*       out    = (float*)d_out;
    if (ws_size >= WS_NEEDED) {
        _Float16* gws = (_Float16*)d_ws;
        float*    sws = (float*)((char*)d_ws + WS_GC_B);
        ctc_stage_kernel<<<dim3(2, Bn), 256, 0, stream>>>(y_true, y_pred, gws, sws);
        ctc_dp_kernel<<<Bn, 64, 0, stream>>>(y_true, gws, sws, out);
    } else {
        ctc_fused_kernel<<<Bn, 512, 0, stream>>>(y_true, y_pred, out);
    }
}